// Round 10
// baseline (203.158 us; speedup 1.0000x reference)
//
#include <hip/hip_runtime.h>

// ---------------- problem constants ----------------
#define N_USER   100000
#define N_SELLER 50000
#define NEDGE    640000
#define DU       128
#define DS       64
#define HH       128
#define BSZ      50000

// partitioned graph build
#define ECHUNK   2048
#define NBLK     313          // ceil(NEDGE/ECHUNK)
#define PW       128          // partition width (nodes)
#define NPART_B  391          // ceil(N_SELLER/PW)
#define NPART_R  782          // ceil(N_USER/PW)

// fused scatter+cvt+prep grid split
#define CVT_BLK  15625        // (100000*128/4 + 50000*64/4)/256
#define PREP_BLK 448          // 114688/256

#define NB1_BUY  391          // ceil(50000/128)
#define NB1_REV  782          // ceil(100000/128)
#define NB2      391

#define AGG1_BUY_BLK 12500    // ceil(50000/4)
#define AGG1_REV_BLK 25000    // ceil(100000/4)
#define AGG2_BLK     12500

typedef unsigned short ushort_t;
typedef __attribute__((ext_vector_type(4))) unsigned short u16x4;
typedef __attribute__((ext_vector_type(8))) unsigned short u16x8;
typedef __attribute__((ext_vector_type(8))) short bf16x8;
typedef __attribute__((ext_vector_type(4))) float f32x4;

__device__ __forceinline__ float bf2f(ushort_t u) {
  union { unsigned int i; float f; } v; v.i = ((unsigned int)u) << 16; return v.f;
}
__device__ __forceinline__ ushort_t f2bf(float f) {
  union { float f; unsigned int i; } v; v.f = f;
  unsigned int x = v.i;
  unsigned int r = x + 0x7FFFu + ((x >> 16) & 1u);
  return (ushort_t)(r >> 16);
}
__device__ __forceinline__ float u2f(unsigned int u) {
  union { unsigned int i; float f; } v; v.i = u; return v.f;
}

// ---------------- K0: partition histograms ----------------
__global__ void __launch_bounds__(256) k_hist(
    const int* __restrict__ dst_buy, const int* __restrict__ dst_rev,
    int* __restrict__ H_buy, int* __restrict__ H_rev) {
  __shared__ int lh[NPART_R];
  int b = blockIdx.x, t = threadIdx.x;
  bool is_buy = b < NBLK;
  int bb = is_buy ? b : b - NBLK;
  const int* dst = is_buy ? dst_buy : dst_rev;
  int* H = is_buy ? H_buy : H_rev;
  int np = is_buy ? NPART_B : NPART_R;
  for (int i = t; i < np; i += 256) lh[i] = 0;
  __syncthreads();
  int base = bb * ECHUNK;
#pragma unroll
  for (int i = 0; i < 8; ++i) {
    int e = base + i * 256 + t;
    if (e < NEDGE) atomicAdd(&lh[dst[e] >> 7], 1);
  }
  __syncthreads();
  for (int p = t; p < np; p += 256) H[p * NBLK + bb] = lh[p];
}

// ---------------- K2: in-place exclusive scan of each partition row over blocks --------
__global__ void __launch_bounds__(256) k_rowscan(
    int* __restrict__ H_buy, int* __restrict__ H_rev,
    int* __restrict__ rowtot_buy, int* __restrict__ rowtot_rev) {
  __shared__ int lds[256];
  int p = blockIdx.x, t = threadIdx.x;
  int* H; int* rowtot; int row;
  if (p < NPART_B) { H = H_buy; rowtot = rowtot_buy; row = p; }
  else             { H = H_rev; rowtot = rowtot_rev; row = p - NPART_B; }
  int i0 = 2 * t, i1 = 2 * t + 1;
  int v0 = (i0 < NBLK) ? H[row * NBLK + i0] : 0;
  int v1 = (i1 < NBLK) ? H[row * NBLK + i1] : 0;
  int tot = v0 + v1;
  lds[t] = tot;
  __syncthreads();
  for (int d = 1; d < 256; d <<= 1) {
    int x = (t >= d) ? lds[t - d] : 0;
    __syncthreads();
    lds[t] += x;
    __syncthreads();
  }
  int excl = lds[t] - tot;
  if (i0 < NBLK) H[row * NBLK + i0] = excl;
  if (i1 < NBLK) H[row * NBLK + i1] = excl + v0;
  if (t == 255) rowtot[row] = lds[255];
}

// ---------------- K3: scan row totals -> partition starts ----------------
__global__ void __launch_bounds__(256) k_colscan(
    const int* __restrict__ rowtot_buy, const int* __restrict__ rowtot_rev,
    int* __restrict__ pstart_buy, int* __restrict__ pstart_rev) {
  __shared__ int lds[256];
  const int* rt; int* ps; int n;
  if (blockIdx.x == 0) { rt = rowtot_buy; ps = pstart_buy; n = NPART_B; }
  else                 { rt = rowtot_rev; ps = pstart_rev; n = NPART_R; }
  int t = threadIdx.x;
  int v[4]; int tot = 0;
#pragma unroll
  for (int i = 0; i < 4; ++i) { int idx = t * 4 + i; v[i] = (idx < n) ? rt[idx] : 0; tot += v[i]; }
  lds[t] = tot;
  __syncthreads();
  for (int d = 1; d < 256; d <<= 1) {
    int x = (t >= d) ? lds[t - d] : 0;
    __syncthreads();
    lds[t] += x;
    __syncthreads();
  }
  int excl = lds[t] - tot;
#pragma unroll
  for (int i = 0; i < 4; ++i) {
    int idx = t * 4 + i;
    if (idx < n) { ps[idx] = excl; excl += v[i]; }
  }
  if (t == 255) ps[n] = lds[255];
}

// ---------------- K4: fused {partition scatter + cvt + weight pack} ----------------
// entry packing: (local_dst << 20) | src   (src < 2^17, local_dst < 2^7)
__global__ void __launch_bounds__(256) k_scat_cvt_prep(
    const int* __restrict__ src_buy, const int* __restrict__ dst_buy,
    const int* __restrict__ src_rev, const int* __restrict__ dst_rev,
    const int* __restrict__ H_buy, const int* __restrict__ H_rev,
    const int* __restrict__ pstart_buy, const int* __restrict__ pstart_rev,
    unsigned int* __restrict__ part_buy, unsigned int* __restrict__ part_rev,
    const float* __restrict__ x_user, ushort_t* __restrict__ xu_bf,
    const float* __restrict__ x_seller, ushort_t* __restrict__ xs_bf,
    const float* __restrict__ Wl1b, const float* __restrict__ Wr1b, ushort_t* __restrict__ o1b,
    const float* __restrict__ Wl1r, const float* __restrict__ Wr1r, ushort_t* __restrict__ o1r,
    const float* __restrict__ Wl2b, const float* __restrict__ Wr2b, ushort_t* __restrict__ o2b,
    const float* __restrict__ Wl2r, const float* __restrict__ Wr2r, ushort_t* __restrict__ o2r) {
  __shared__ int lc[NPART_R];
  int b = blockIdx.x, t = threadIdx.x;
  if (b < 2 * NBLK) {
    bool is_buy = b < NBLK;
    int bb = is_buy ? b : b - NBLK;
    const int* src = is_buy ? src_buy : src_rev;
    const int* dst = is_buy ? dst_buy : dst_rev;
    const int* H   = is_buy ? H_buy : H_rev;
    const int* ps  = is_buy ? pstart_buy : pstart_rev;
    unsigned int* part = is_buy ? part_buy : part_rev;
    int np = is_buy ? NPART_B : NPART_R;
    for (int i = t; i < np; i += 256) lc[i] = 0;
    __syncthreads();
    int base = bb * ECHUNK;
#pragma unroll
    for (int i = 0; i < 8; ++i) {
      int e = base + i * 256 + t;
      if (e < NEDGE) {
        int d = dst[e], s = src[e];
        int p = d >> 7;
        int r = atomicAdd(&lc[p], 1);
        int pos = ps[p] + H[p * NBLK + bb] + r;
        part[pos] = ((unsigned int)(d & (PW - 1)) << 20) | (unsigned int)s;
      }
    }
  } else if (b < 2 * NBLK + CVT_BLK) {
    int idx = (b - 2 * NBLK) * 256 + t;
    const int na4 = N_USER * DU / 4;
    const float* in; ushort_t* out;
    if (idx < na4) { in = x_user + idx * 4; out = xu_bf + idx * 4; }
    else { idx -= na4; in = x_seller + idx * 4; out = xs_bf + idx * 4; }
    float4 v = *(const float4*)in;
    u16x4 r;
    r.x = f2bf(v.x); r.y = f2bf(v.y); r.z = f2bf(v.z); r.w = f2bf(v.w);
    *(u16x4*)out = r;
  } else {
    int idx = (b - 2 * NBLK - CVT_BLK) * 256 + t;
    const float *Wl, *Wr; ushort_t* out; int D1;
    if (idx < 24576)      { Wl = Wl1b; Wr = Wr1b; out = o1b; D1 = 128; }
    else if (idx < 49152) { idx -= 24576; Wl = Wl1r; Wr = Wr1r; out = o1r; D1 = 64; }
    else if (idx < 81920) { idx -= 49152; Wl = Wl2b; Wr = Wr2b; out = o2b; D1 = 128; }
    else                  { idx -= 81920; Wl = Wl2r; Wr = Wr2r; out = o2r; D1 = 128; }
    int f = idx >> 9;
    int r = idx & 511;
    int l = r >> 3;
    int j = r & 7;
    int kcidx = f >> 3;
    int c = f & 7;
    int h = (l & 15) + c * 16;
    int k = kcidx * 32 + (l >> 4) * 8 + j;
    float w = (k < D1) ? Wl[k * HH + h] : Wr[(k - D1) * HH + h];
    out[idx] = f2bf(w);
  }
}

// ---------------- K5: per-partition CSR build (LDS count + scan) ----------------
__global__ void __launch_bounds__(256) k_csr(
    const unsigned int* __restrict__ part_buy, const unsigned int* __restrict__ part_rev,
    const int* __restrict__ pstart_buy, const int* __restrict__ pstart_rev,
    int* __restrict__ off_buy, int* __restrict__ off_rev,
    int* __restrict__ csr_buy, int* __restrict__ csr_rev) {
  __shared__ int lcnt[PW], loff[PW], sc[PW];
  int B = blockIdx.x, t = threadIdx.x;
  bool is_buy = B < NPART_B;
  int p = is_buy ? B : B - NPART_B;
  const unsigned int* part = is_buy ? part_buy : part_rev;
  const int* ps = is_buy ? pstart_buy : pstart_rev;
  int* off = is_buy ? off_buy : off_rev;
  int* csr = is_buy ? csr_buy : csr_rev;
  int nnode = is_buy ? N_SELLER : N_USER;
  int s0 = ps[p], s1 = ps[p + 1];
  if (t < PW) lcnt[t] = 0;
  __syncthreads();
  for (int e = s0 + t; e < s1; e += 256) {
    int d = (int)(part[e] >> 20);
    atomicAdd(&lcnt[d], 1);
  }
  __syncthreads();
  int v = (t < PW) ? lcnt[t] : 0;
  if (t < PW) sc[t] = v;
  __syncthreads();
  for (int d = 1; d < PW; d <<= 1) {
    int x = (t >= d && t < PW) ? sc[t - d] : 0;
    __syncthreads();
    if (t < PW) sc[t] += x;
    __syncthreads();
  }
  if (t < PW) {
    loff[t] = sc[t] - v;
    int node = p * PW + t;
    if (node < nnode) off[node] = s0 + loff[t];
    lcnt[t] = 0;
  }
  if (B == 0 && t == 0) { off_buy[N_SELLER] = NEDGE; off_rev[N_USER] = NEDGE; }
  __syncthreads();
  for (int e = s0 + t; e < s1; e += 256) {
    unsigned int pk = part[e];
    int l = (int)(pk >> 20);
    int r = atomicAdd(&lcnt[l], 1);
    csr[s0 + loff[l] + r] = (int)(pk & 0xFFFFFu);
  }
}

// ---------------- CSR mean aggregation (VALU-slim: guard-free main + f32x2 acc) -------
template <int D, int U>
__device__ __forceinline__ void agg_body(
    int blk, const ushort_t* __restrict__ X,
    const int* __restrict__ off, const int* __restrict__ csr,
    const int* __restrict__ idxs, int nrows,
    ushort_t* __restrict__ out) {
  constexpr int LPR = D / 8;
  constexpr int EPW = 64 / LPR;
  int wave = threadIdx.x >> 6;
  int lane = threadIdx.x & 63;
  int n = blk * 4 + wave;
  if (n >= nrows) return;
  int node = idxs ? idxs[n] : n;
  int g = lane / LPR;
  int c = (lane % LPR) * 8;
  int i0 = off[node], i1 = off[node + 1];
  const ushort_t* Xc = X + c;

  float2 acc[4];
#pragma unroll
  for (int q = 0; q < 4; ++q) acc[q] = (float2){0.f, 0.f};

  int i = i0 + g;
  // main loop: all U slots in-bounds, zero guard logic
  for (; i + (U - 1) * EPW < i1; i += U * EPW) {
    int idxv[U];
#pragma unroll
    for (int u = 0; u < U; ++u) idxv[u] = csr[i + u * EPW];
    uint4 v[U];
#pragma unroll
    for (int u = 0; u < U; ++u)
      v[u] = *(const uint4*)(Xc + (size_t)idxv[u] * D);
#pragma unroll
    for (int u = 0; u < U; ++u) {
      acc[0] += (float2){u2f(v[u].x << 16), u2f(v[u].x & 0xFFFF0000u)};
      acc[1] += (float2){u2f(v[u].y << 16), u2f(v[u].y & 0xFFFF0000u)};
      acc[2] += (float2){u2f(v[u].z << 16), u2f(v[u].z & 0xFFFF0000u)};
      acc[3] += (float2){u2f(v[u].w << 16), u2f(v[u].w & 0xFFFF0000u)};
    }
  }
  // tail
  for (; i < i1; i += EPW) {
    int s = csr[i];
    uint4 v = *(const uint4*)(Xc + (size_t)s * D);
    acc[0] += (float2){u2f(v.x << 16), u2f(v.x & 0xFFFF0000u)};
    acc[1] += (float2){u2f(v.y << 16), u2f(v.y & 0xFFFF0000u)};
    acc[2] += (float2){u2f(v.z << 16), u2f(v.z & 0xFFFF0000u)};
    acc[3] += (float2){u2f(v.w << 16), u2f(v.w & 0xFFFF0000u)};
  }

#pragma unroll
  for (int mm = LPR; mm < 64; mm <<= 1) {
#pragma unroll
    for (int q = 0; q < 4; ++q) {
      acc[q].x += __shfl_xor(acc[q].x, mm);
      acc[q].y += __shfl_xor(acc[q].y, mm);
    }
  }

  if (g == 0) {
    int deg = i1 - i0;
    float inv = 1.f / (float)(deg > 0 ? deg : 1);
    u16x8 r;
#pragma unroll
    for (int q = 0; q < 4; ++q) {
      r[2 * q]     = f2bf(acc[q].x * inv);
      r[2 * q + 1] = f2bf(acc[q].y * inv);
    }
    *(u16x8*)(out + (size_t)n * D + c) = r;
  }
}

__global__ void __launch_bounds__(256) agg_layer1(
    const ushort_t* __restrict__ xu_bf, const ushort_t* __restrict__ xs_bf,
    const int* __restrict__ off_buy, const int* __restrict__ csr_buy,
    const int* __restrict__ off_rev, const int* __restrict__ csr_rev,
    ushort_t* __restrict__ mean_buy, ushort_t* __restrict__ mean_rev) {
  int b = blockIdx.x;
  if (b < AGG1_BUY_BLK)
    agg_body<128, 2>(b, xu_bf, off_buy, csr_buy, nullptr, N_SELLER, mean_buy);
  else
    agg_body<64, 2>(b - AGG1_BUY_BLK, xs_bf, off_rev, csr_rev, nullptr, N_USER, mean_rev);
}

__global__ void __launch_bounds__(256) agg_layer2(
    const ushort_t* __restrict__ u1, const ushort_t* __restrict__ s1,
    const int* __restrict__ off_buy, const int* __restrict__ csr_buy,
    const int* __restrict__ off_rev, const int* __restrict__ csr_rev,
    const int* __restrict__ mask_seller, const int* __restrict__ mask_user,
    ushort_t* __restrict__ mean_buy, ushort_t* __restrict__ mean_rev) {
  int b = blockIdx.x;
  if (b < AGG2_BLK)
    agg_body<128, 2>(b, u1, off_buy, csr_buy, mask_seller, BSZ, mean_buy);
  else
    agg_body<128, 2>(b - AGG2_BLK, s1, off_rev, csr_rev, mask_user, BSZ, mean_rev);
}

// ---------------- LDS-staged fused SAGE GEMM (device body) ----------------
template <int K, bool HEAD>
__device__ __forceinline__ void gemm_body(
    int blk, ushort_t* lds,
    const ushort_t* __restrict__ A1, int ld1, int D1, const int* __restrict__ mask1,
    const ushort_t* __restrict__ A2, int ld2, const int* __restrict__ mask2,
    const ushort_t* __restrict__ Wf, const float* __restrict__ bias,
    ushort_t* __restrict__ out, float* __restrict__ partial,
    const float* __restrict__ wlin_seg, int M) {
  constexpr int NCH = K / 32;
  int t = threadIdx.x;
  int wave = t >> 6;
  int lane = t & 63;

  constexpr int ITERS = (HH * K * 2) / 4096;
#pragma unroll
  for (int i = 0; i < ITERS; ++i) {
    const ushort_t* g = Wf + i * 2048 + t * 8;
    ushort_t* l = lds + i * 2048 + wave * 512;
    __builtin_amdgcn_global_load_lds((const __attribute__((address_space(1))) void*)g,
                                     (__attribute__((address_space(3))) void*)l, 16, 0, 0);
  }

  int row0 = blk * 128 + wave * 32;
  int kb = (lane >> 4) << 3;
  bf16x8 af[2][NCH];
#pragma unroll
  for (int s = 0; s < 2; ++s) {
    int r = row0 + s * 16 + (lane & 15);
    int rsafe = r < M ? r : M - 1;
    int a1 = mask1 ? mask1[rsafe] : rsafe;
    int a2 = mask2 ? mask2[rsafe] : rsafe;
#pragma unroll
    for (int kc = 0; kc < NCH; ++kc) {
      int k = kc * 32 + kb;
      const ushort_t* ap = (k < D1) ? (A1 + (size_t)a1 * ld1 + k)
                                    : (A2 + (size_t)a2 * ld2 + (k - D1));
      af[s][kc] = *(const bf16x8*)ap;
    }
  }

  f32x4 acc[2][8];
#pragma unroll
  for (int s = 0; s < 2; ++s)
#pragma unroll
    for (int c = 0; c < 8; ++c) acc[s][c] = (f32x4){0.f, 0.f, 0.f, 0.f};

  __syncthreads();

#pragma unroll
  for (int kc = 0; kc < NCH; ++kc) {
#pragma unroll
    for (int c = 0; c < 8; ++c) {
      bf16x8 bf = *(const bf16x8*)(lds + ((kc * 8 + c) * 512 + lane * 8));
      acc[0][c] = __builtin_amdgcn_mfma_f32_16x16x32_bf16(af[0][kc], bf, acc[0][c], 0, 0, 0);
      acc[1][c] = __builtin_amdgcn_mfma_f32_16x16x32_bf16(af[1][kc], bf, acc[1][c], 0, 0, 0);
    }
  }

  int colb = lane & 15;
  if constexpr (!HEAD) {
#pragma unroll
    for (int s = 0; s < 2; ++s) {
      int rbase = row0 + s * 16 + ((lane >> 4) << 2);
#pragma unroll
      for (int c = 0; c < 8; ++c) {
        int col = c * 16 + colb;
        float bv = bias[col];
#pragma unroll
        for (int j = 0; j < 4; ++j) {
          int rout = rbase + j;
          if (rout < M) {
            float v = fmaxf(acc[s][c][j] + bv, 0.f);
            out[(size_t)rout * HH + col] = f2bf(v);
          }
        }
      }
    }
  } else {
    float wl[8], bv[8];
#pragma unroll
    for (int c = 0; c < 8; ++c) {
      wl[c] = wlin_seg[c * 16 + colb];
      bv[c] = bias[c * 16 + colb];
    }
#pragma unroll
    for (int s = 0; s < 2; ++s) {
      float p0 = 0.f, p1 = 0.f, p2 = 0.f, p3 = 0.f;
#pragma unroll
      for (int c = 0; c < 8; ++c) {
        p0 += fmaxf(acc[s][c][0] + bv[c], 0.f) * wl[c];
        p1 += fmaxf(acc[s][c][1] + bv[c], 0.f) * wl[c];
        p2 += fmaxf(acc[s][c][2] + bv[c], 0.f) * wl[c];
        p3 += fmaxf(acc[s][c][3] + bv[c], 0.f) * wl[c];
      }
#pragma unroll
      for (int m = 1; m < 16; m <<= 1) {
        p0 += __shfl_xor(p0, m);
        p1 += __shfl_xor(p1, m);
        p2 += __shfl_xor(p2, m);
        p3 += __shfl_xor(p3, m);
      }
      if (colb == 0) {
        int rbase = row0 + s * 16 + ((lane >> 4) << 2);
        if (rbase + 0 < M) partial[rbase + 0] = p0;
        if (rbase + 1 < M) partial[rbase + 1] = p1;
        if (rbase + 2 < M) partial[rbase + 2] = p2;
        if (rbase + 3 < M) partial[rbase + 3] = p3;
      }
    }
  }
}

__global__ void __launch_bounds__(256) gemm_layer1(
    const ushort_t* __restrict__ mean_buy, const ushort_t* __restrict__ xs_bf,
    const ushort_t* __restrict__ mean_rev, const ushort_t* __restrict__ xu_bf,
    const ushort_t* __restrict__ wt1_buy, const float* __restrict__ b1_buy,
    const ushort_t* __restrict__ wt1_rev, const float* __restrict__ b1_rev,
    ushort_t* __restrict__ s1, ushort_t* __restrict__ u1) {
  __shared__ ushort_t lds[HH * 192];
  int b = blockIdx.x;
  if (b < NB1_BUY)
    gemm_body<192, false>(b, lds, mean_buy, 128, 128, nullptr, xs_bf, 64, nullptr,
                          wt1_buy, b1_buy, s1, nullptr, nullptr, N_SELLER);
  else
    gemm_body<192, false>(b - NB1_BUY, lds, mean_rev, 64, 64, nullptr, xu_bf, 128, nullptr,
                          wt1_rev, b1_rev, u1, nullptr, nullptr, N_USER);
}

__global__ void __launch_bounds__(256) gemm_layer2(
    const ushort_t* __restrict__ mean_buy, const ushort_t* __restrict__ s1,
    const ushort_t* __restrict__ mean_rev, const ushort_t* __restrict__ u1,
    const int* __restrict__ mask_seller, const int* __restrict__ mask_user,
    const ushort_t* __restrict__ wt2_buy, const float* __restrict__ b2_buy,
    const ushort_t* __restrict__ wt2_rev, const float* __restrict__ b2_rev,
    const float* __restrict__ wlin,
    float* __restrict__ ps, float* __restrict__ pu) {
  __shared__ ushort_t lds[HH * 256];
  int b = blockIdx.x;
  if (b < NB2)
    gemm_body<256, true>(b, lds, mean_buy, 128, 128, nullptr, s1, 128, mask_seller,
                         wt2_buy, b2_buy, nullptr, ps, wlin + 128, BSZ);
  else
    gemm_body<256, true>(b - NB2, lds, mean_rev, 128, 128, nullptr, u1, 128, mask_user,
                         wt2_rev, b2_rev, nullptr, pu, wlin, BSZ);
}

// ---------------- final head ----------------
__global__ void head_fin(const float* __restrict__ pu, const float* __restrict__ ps,
                         const float* __restrict__ blin, float* __restrict__ out) {
  int i = blockIdx.x * 256 + threadIdx.x;
  if (i < BSZ) {
    float z = pu[i] + ps[i] + blin[0];
    out[i] = 1.f / (1.f + expf(-z));
  }
}

// ---------------- launch ----------------
extern "C" void kernel_launch(void* const* d_in, const int* in_sizes, int n_in,
                              void* d_out, int out_size, void* d_ws, size_t ws_size,
                              hipStream_t stream) {
  const float* x_user    = (const float*)d_in[0];
  const float* x_seller  = (const float*)d_in[1];
  const int* src_buy  = (const int*)d_in[2];
  const int* dst_buy  = (const int*)d_in[3];
  const int* src_rev  = (const int*)d_in[4];
  const int* dst_rev  = (const int*)d_in[5];
  const int* mask_user   = (const int*)d_in[6];
  const int* mask_seller = (const int*)d_in[7];
  const float* Wl1_buy = (const float*)d_in[8];
  const float* Wr1_buy = (const float*)d_in[9];
  const float* b1_buy  = (const float*)d_in[10];
  const float* Wl1_rev = (const float*)d_in[11];
  const float* Wr1_rev = (const float*)d_in[12];
  const float* b1_rev  = (const float*)d_in[13];
  const float* Wl2_buy = (const float*)d_in[14];
  const float* Wr2_buy = (const float*)d_in[15];
  const float* b2_buy  = (const float*)d_in[16];
  const float* Wl2_rev = (const float*)d_in[17];
  const float* Wr2_rev = (const float*)d_in[18];
  const float* b2_rev  = (const float*)d_in[19];
  const float* Wlin    = (const float*)d_in[20];
  const float* blin    = (const float*)d_in[21];

  // ---- workspace layout ----
  char* ws = (char*)d_ws;
  size_t o = 0;
  auto alloc = [&](size_t bytes) { size_t p = o; o += (bytes + 255) & ~(size_t)255; return p; };
  size_t wt1_buy_o = alloc(HH * 192 * 2);
  size_t wt1_rev_o = alloc(HH * 192 * 2);
  size_t wt2_buy_o = alloc(HH * 256 * 2);
  size_t wt2_rev_o = alloc(HH * 256 * 2);
  size_t H_buy_o = alloc((size_t)NPART_B * NBLK * 4);
  size_t H_rev_o = alloc((size_t)NPART_R * NBLK * 4);
  size_t rowtot_buy_o = alloc(NPART_B * 4);
  size_t rowtot_rev_o = alloc(NPART_R * 4);
  size_t pstart_buy_o = alloc((NPART_B + 1) * 4);
  size_t pstart_rev_o = alloc((NPART_R + 1) * 4);
  size_t part_buy_o = alloc((size_t)NEDGE * 4);
  size_t part_rev_o = alloc((size_t)NEDGE * 4);
  size_t off_buy_o = alloc((size_t)(N_SELLER + 1) * 4);
  size_t off_rev_o = alloc((size_t)(N_USER + 1) * 4);
  size_t csr_buy_o = alloc((size_t)NEDGE * 4);
  size_t csr_rev_o = alloc((size_t)NEDGE * 4);
  size_t xu_bf_o = alloc((size_t)N_USER * DU * 2);
  size_t xs_bf_o = alloc((size_t)N_SELLER * DS * 2);
  size_t mean_buy_o = alloc((size_t)N_SELLER * 128 * 2);
  size_t mean_rev_o = alloc((size_t)N_USER * 64 * 2);
  size_t s1_o = alloc((size_t)N_SELLER * HH * 2);
  size_t u1_o = alloc((size_t)N_USER * HH * 2);
  size_t ps_o = alloc((size_t)50048 * 4);
  size_t pu_o = alloc((size_t)50048 * 4);
  (void)ws_size;

  ushort_t* wt1_buy = (ushort_t*)(ws + wt1_buy_o);
  ushort_t* wt1_rev = (ushort_t*)(ws + wt1_rev_o);
  ushort_t* wt2_buy = (ushort_t*)(ws + wt2_buy_o);
  ushort_t* wt2_rev = (ushort_t*)(ws + wt2_rev_o);
  int* H_buy = (int*)(ws + H_buy_o);
  int* H_rev = (int*)(ws + H_rev_o);
  int* rowtot_buy = (int*)(ws + rowtot_buy_o);
  int* rowtot_rev = (int*)(ws + rowtot_rev_o);
  int* pstart_buy = (int*)(ws + pstart_buy_o);
  int* pstart_rev = (int*)(ws + pstart_rev_o);
  unsigned int* part_buy = (unsigned int*)(ws + part_buy_o);
  unsigned int* part_rev = (unsigned int*)(ws + part_rev_o);
  int* off_buy = (int*)(ws + off_buy_o);
  int* off_rev = (int*)(ws + off_rev_o);
  int* csr_buy = (int*)(ws + csr_buy_o);
  int* csr_rev = (int*)(ws + csr_rev_o);
  ushort_t* xu_bf = (ushort_t*)(ws + xu_bf_o);
  ushort_t* xs_bf = (ushort_t*)(ws + xs_bf_o);
  ushort_t* mean_buy = (ushort_t*)(ws + mean_buy_o);
  ushort_t* mean_rev = (ushort_t*)(ws + mean_rev_o);
  ushort_t* s1 = (ushort_t*)(ws + s1_o);
  ushort_t* u1 = (ushort_t*)(ws + u1_o);
  float* ps = (float*)(ws + ps_o);
  float* pu = (float*)(ws + pu_o);

  // ---- graph build: hist -> scans -> {scatter + cvt + prep} -> csr ----
  k_hist<<<2 * NBLK, 256, 0, stream>>>(dst_buy, dst_rev, H_buy, H_rev);
  k_rowscan<<<NPART_B + NPART_R, 256, 0, stream>>>(H_buy, H_rev, rowtot_buy, rowtot_rev);
  k_colscan<<<2, 256, 0, stream>>>(rowtot_buy, rowtot_rev, pstart_buy, pstart_rev);
  k_scat_cvt_prep<<<2 * NBLK + CVT_BLK + PREP_BLK, 256, 0, stream>>>(
      src_buy, dst_buy, src_rev, dst_rev, H_buy, H_rev, pstart_buy, pstart_rev,
      part_buy, part_rev,
      x_user, xu_bf, x_seller, xs_bf,
      Wl1_buy, Wr1_buy, wt1_buy, Wl1_rev, Wr1_rev, wt1_rev,
      Wl2_buy, Wr2_buy, wt2_buy, Wl2_rev, Wr2_rev, wt2_rev);
  k_csr<<<NPART_B + NPART_R, 256, 0, stream>>>(part_buy, part_rev, pstart_buy, pstart_rev,
                                               off_buy, off_rev, csr_buy, csr_rev);

  // ---- layer 1 ----
  agg_layer1<<<AGG1_BUY_BLK + AGG1_REV_BLK, 256, 0, stream>>>(
      xu_bf, xs_bf, off_buy, csr_buy, off_rev, csr_rev, mean_buy, mean_rev);
  gemm_layer1<<<NB1_BUY + NB1_REV, 256, 0, stream>>>(
      mean_buy, xs_bf, mean_rev, xu_bf, wt1_buy, b1_buy, wt1_rev, b1_rev, s1, u1);

  // ---- layer 2 (masked rows only, head fused) ----
  agg_layer2<<<AGG2_BLK + AGG2_BLK, 256, 0, stream>>>(
      u1, s1, off_buy, csr_buy, off_rev, csr_rev, mask_seller, mask_user,
      mean_buy, mean_rev);
  gemm_layer2<<<NB2 + NB2, 256, 0, stream>>>(
      mean_buy, s1, mean_rev, u1, mask_seller, mask_user,
      wt2_buy, b2_buy, wt2_rev, b2_rev, Wlin, ps, pu);

  // ---- final head ----
  head_fin<<<(BSZ + 255) / 256, 256, 0, stream>>>(pu, ps, blin, (float*)d_out);
}